// Round 2
// baseline (420.628 us; speedup 1.0000x reference)
//
#include <hip/hip_runtime.h>

// ---------------------------------------------------------------------------
// IntraStockCorrelation: N=4096 stocks, H=512, C=16 clusters, K=6 subclusters
// softmax(scores + log(gram/max + 1e-10)) == es*g / sum(es*g),
//   es = exp(scores - rowmax(scores)) (shared over k), g = gram*inv + 1e-10
// Gram is PSD -> max entry is on the diagonal -> diag-only max reduction.
// ---------------------------------------------------------------------------

typedef _Float16 f16;
typedef _Float16 v8h __attribute__((ext_vector_type(8)));
typedef _Float16 v4h __attribute__((ext_vector_type(4)));
typedef float f32x4 __attribute__((ext_vector_type(4)));

#define MFMA_F16(a, b, c) __builtin_amdgcn_mfma_f32_16x16x32_f16(a, b, c, 0, 0, 0)

#define GLOAD16(gp, lp)                                                        \
  __builtin_amdgcn_global_load_lds(                                            \
      (const __attribute__((address_space(1))) void*)(gp),                     \
      (__attribute__((address_space(3))) void*)(lp), 16, 0, 0)

// -------------------------- small elementwise kernels ----------------------

__global__ void cvt_f16_kernel(const float* __restrict__ in, f16* __restrict__ out, int n4) {
  int i = blockIdx.x * blockDim.x + threadIdx.x;
  if (i < n4) {
    float4 v = ((const float4*)in)[i];
    v4h o = {(f16)v.x, (f16)v.y, (f16)v.z, (f16)v.w};
    ((v4h*)out)[i] = o;
  }
}

// Ab[k][n][c32]: c<cc -> w[n,c]*lat[n,c,k], else 0.  total = 6*4096*32
__global__ void build_A_kernel(const float* __restrict__ wgt, const float* __restrict__ lat,
                               const int* __restrict__ ccp, f16* __restrict__ Ab, int total) {
  int idx = blockIdx.x * blockDim.x + threadIdx.x;
  if (idx >= total) return;
  int cc = ccp[0];
  int k = idx >> 17;           // 4096*32 = 131072
  int rem = idx & 131071;
  int n = rem >> 5;
  int c = rem & 31;
  float v = 0.f;
  if (c < cc) v = wgt[n * 16 + c] * lat[(n * 16 + c) * 6 + k];
  Ab[idx] = (f16)v;
}

// Gram max = max diag = max_n ||A_k[n]||^2.  grid 96 x 256, idx = k*4096 + n.
__global__ void diag_max_kernel(const f16* __restrict__ Ab, unsigned* __restrict__ gmax) {
  int idx = blockIdx.x * 256 + threadIdx.x;   // 0..24575
  int kk = idx >> 12;
  const v8h* p = (const v8h*)(Ab + (size_t)idx * 32);
  float s = 0.f;
#pragma unroll
  for (int q = 0; q < 4; ++q) {
    v8h a = p[q];
#pragma unroll
    for (int j = 0; j < 8; ++j) s += (float)a[j] * (float)a[j];
  }
#pragma unroll
  for (int msk = 1; msk < 64; msk <<= 1) s = fmaxf(s, __shfl_xor(s, msk, 64));
  if ((threadIdx.x & 63) == 0) atomicMax(&gmax[kk], __float_as_uint(s));  // s>=0
}

// -------------------------- generic f16 MFMA GEMM (A @ B^T) ----------------
// A [M x K] row-major f16, B [N x K] row-major f16 (i.e. computes A@B^T).
// MODE 0: outh[row*ldo+col] = (acc + bias[col]) * alpha        (f16)
// MODE 1: VT write: outh[col*4096 + swz(row)] = acc + bias[col] (f16, pre-swizzled)
// MODE 3: outf[row*ldo+col] = acc + bias[col] + resid[(row&4095)*ldo+col] (f32)
// MODE 4: outh[row*ldo+col] = acc                               (f16, no bias)

template <int MODE>
__global__ __launch_bounds__(256, 2) void gemm_bt(
    const f16* __restrict__ A, const f16* __restrict__ B,
    const float* __restrict__ bias, const float* __restrict__ resid,
    float* __restrict__ outf, f16* __restrict__ outh,
    int M, int Nn, int Kd, int ldo, float alpha) {
  __shared__ f16 As[128 * 32];
  __shared__ f16 Bs[128 * 32];
  const int t = threadIdx.x;
  const int w = t >> 6, lane = t & 63, r15 = lane & 15, r4 = lane >> 4;
  const int wr = w >> 1, wc = w & 1;
  const int row0 = blockIdx.x * 128, col0 = blockIdx.y * 128;

  f32x4 acc[4][4] = {};
  const f16* Ap = A + (size_t)(row0 + (t >> 2)) * Kd + (t & 3) * 8;
  const f16* Bp = B + (size_t)(col0 + (t >> 2)) * Kd + (t & 3) * 8;

  for (int k0 = 0; k0 < Kd; k0 += 32) {
    __syncthreads();
    GLOAD16(Ap + k0, &As[t * 8]);
    GLOAD16(Ap + k0 + (size_t)64 * Kd, &As[2048 + t * 8]);
    GLOAD16(Bp + k0, &Bs[t * 8]);
    GLOAD16(Bp + k0 + (size_t)64 * Kd, &Bs[2048 + t * 8]);
    __syncthreads();
    v8h a[4], b[4];
#pragma unroll
    for (int f = 0; f < 4; ++f) a[f] = *(const v8h*)&As[(wr * 64 + f * 16 + r15) * 32 + r4 * 8];
#pragma unroll
    for (int f = 0; f < 4; ++f) b[f] = *(const v8h*)&Bs[(wc * 64 + f * 16 + r15) * 32 + r4 * 8];
#pragma unroll
    for (int i = 0; i < 4; ++i)
#pragma unroll
      for (int j = 0; j < 4; ++j) acc[i][j] = MFMA_F16(a[i], b[j], acc[i][j]);
  }

#pragma unroll
  for (int i = 0; i < 4; ++i) {
#pragma unroll
    for (int j = 0; j < 4; ++j) {
#pragma unroll
      for (int r = 0; r < 4; ++r) {
        int row = row0 + wr * 64 + i * 16 + r4 * 4 + r;
        int col = col0 + wc * 64 + j * 16 + r15;
        float v = acc[i][j][r];
        if constexpr (MODE == 0) {
          outh[(size_t)row * ldo + col] = (f16)((v + bias[col]) * alpha);
        } else if constexpr (MODE == 1) {
          float vv = v + bias[col];
          size_t idx = (size_t)col * 4096 + (size_t)(row & ~31) + (size_t)((row & 31) ^ ((col & 3) << 3));
          outh[idx] = (f16)vv;
        } else if constexpr (MODE == 3) {
          outf[(size_t)row * ldo + col] = v + bias[col] + resid[(size_t)(row & 4095) * ldo + col];
        } else {
          outh[(size_t)row * ldo + col] = (f16)v;
        }
      }
    }
  }
}

// -------------------------- rowmax + exp (f16 scores) ----------------------
__global__ __launch_bounds__(256) void rowmax_exp_kernel(const f16* __restrict__ scores,
                                                         f16* __restrict__ Eexp) {
  const int row = blockIdx.x, t = threadIdx.x;
  const v8h* src = (const v8h*)(scores + (size_t)row * 4096);
  v8h v0 = src[t], v1 = src[t + 256];
  float m = -3.4e38f;
#pragma unroll
  for (int j = 0; j < 8; ++j) m = fmaxf(m, fmaxf((float)v0[j], (float)v1[j]));
#pragma unroll
  for (int msk = 1; msk < 64; msk <<= 1) m = fmaxf(m, __shfl_xor(m, msk, 64));
  __shared__ float red[4];
  const int w = t >> 6, lane = t & 63;
  if (lane == 0) red[w] = m;
  __syncthreads();
  m = fmaxf(fmaxf(red[0], red[1]), fmaxf(red[2], red[3]));
  v8h o0, o1;
#pragma unroll
  for (int j = 0; j < 8; ++j) {
    o0[j] = (f16)__expf((float)v0[j] - m);
    o1[j] = (f16)__expf((float)v1[j] - m);
  }
  v8h* dst = (v8h*)(Eexp + (size_t)row * 4096);
  dst[t] = o0;
  dst[t + 256] = o1;
}

// -------------------------- fused mask+softmax+PV --------------------------
// grid (64, 6) remapped for XCD locality; block = 512 thr (8 waves).
// Block: 64 rows x full H=512. Per 32-m chunk: gram MFMA -> P = E*(g*inv+1e-10)
// (f32 rowsum) -> swizzled LDS -> 16 PV MFMAs/wave. Epilogue divides by denom.
__global__ __launch_bounds__(512, 2) void attn_pv_kernel(
    const f16* __restrict__ Eexp, const f16* __restrict__ VT,
    const f16* __restrict__ Ab, const unsigned* __restrict__ gmax,
    f16* __restrict__ ctx) {
  __shared__ f16 Vt_s[512 * 32];  // 32KB, pre-swizzled in global
  __shared__ f16 E_s[64 * 32];
  __shared__ f16 P_s[64 * 32];    // XOR-swizzled
  __shared__ f16 Ar_s[64 * 32];
  __shared__ f16 Ac_s[32 * 32];
  __shared__ float denom_s[128];

  const int t = threadIdx.x;
  const int w = t >> 6, lane = t & 63, r15 = lane & 15, r4 = lane >> 4;
  const int fn = w & 3, fm = w >> 2;  // gram-production role

  // XCD-locality remap: all 6 k-variants of a row strip land on one XCD.
  int d = blockIdx.x + gridDim.x * blockIdx.y;  // 0..383
  int l = (d & 7) * 48 + (d >> 3);
  int r_tile = l / 6;
  int kk = l - r_tile * 6;
  const int row0 = r_tile * 64;

  const float inv = 1.f / (__uint_as_float(gmax[kk]) + 1e-8f);

  f32x4 acc[4][4] = {};
  float dpart[4] = {0.f, 0.f, 0.f, 0.f};
  f32x4 zero4 = {};

  if (t < 256)
    GLOAD16(Ab + ((size_t)(kk * 4096 + row0 + (t >> 2))) * 32 + (t & 3) * 8, &Ar_s[t * 8]);

  for (int mc = 0; mc < 128; ++mc) {
    const int m0 = mc * 32;
    // ---- stage (prev iteration's LDS reads fenced by loop-end barrier) ----
#pragma unroll
    for (int i = 0; i < 4; ++i)
      GLOAD16(VT + ((size_t)(i * 128 + (t >> 2))) * 4096 + m0 + (t & 3) * 8, &Vt_s[i * 4096 + t * 8]);
    if (t < 256)
      GLOAD16(Eexp + ((size_t)(row0 + (t >> 2))) * 4096 + m0 + (t & 3) * 8, &E_s[t * 8]);
    if (t < 128)
      GLOAD16(Ab + ((size_t)(kk * 4096 + m0 + (t >> 2))) * 32 + (t & 3) * 8, &Ac_s[t * 8]);
    __syncthreads();
    // ---- gram + P production ----
    v8h ga = *(const v8h*)&Ar_s[(fn * 16 + r15) * 32 + r4 * 8];
    v8h gb = *(const v8h*)&Ac_s[(fm * 16 + r15) * 32 + r4 * 8];
    f32x4 g = MFMA_F16(ga, gb, zero4);
#pragma unroll
    for (int r = 0; r < 4; ++r) {
      int nl = fn * 16 + r4 * 4 + r;
      int ml = fm * 16 + r15;
      float e = (float)E_s[nl * 32 + ml];
      float p = e * (g[r] * inv + 1e-10f);
      dpart[r] += p;
      P_s[nl * 32 + (ml ^ ((nl & 3) << 3))] = (f16)p;
    }
    __syncthreads();
    // ---- PV ----
    v8h pa[4], vb[4];
#pragma unroll
    for (int f = 0; f < 4; ++f) {
      int n2 = f * 16 + r15;
      pa[f] = *(const v8h*)&P_s[n2 * 32 + ((r4 * 8) ^ ((n2 & 3) << 3))];
      int hl = w * 64 + f * 16 + r15;
      vb[f] = *(const v8h*)&Vt_s[hl * 32 + ((r4 * 8) ^ ((hl & 3) << 3))];
    }
#pragma unroll
    for (int i = 0; i < 4; ++i)
#pragma unroll
      for (int j = 0; j < 4; ++j) acc[i][j] = MFMA_F16(pa[i], vb[j], acc[i][j]);
    __syncthreads();
  }

  // ---- denominators ----
#pragma unroll
  for (int r = 0; r < 4; ++r) {
#pragma unroll
    for (int msk = 1; msk < 16; msk <<= 1) dpart[r] += __shfl_xor(dpart[r], msk, 64);
  }
  if (r15 == 0) {
#pragma unroll
    for (int r = 0; r < 4; ++r) denom_s[fm * 64 + fn * 16 + r4 * 4 + r] = dpart[r];
  }
  __syncthreads();
#pragma unroll
  for (int i = 0; i < 4; ++i) {
#pragma unroll
    for (int r = 0; r < 4; ++r) {
      int n = i * 16 + r4 * 4 + r;
      float invd = 1.f / (denom_s[n] + denom_s[64 + n]);
#pragma unroll
      for (int j = 0; j < 4; ++j) {
        ctx[((size_t)(kk * 4096 + row0 + n)) * 512 + w * 64 + j * 16 + r15] =
            (f16)(acc[i][j][r] * invd);
      }
    }
  }
}

// -------------------------- LayerNorm --------------------------------------
__global__ __launch_bounds__(256) void ln_kernel(float* __restrict__ out,
                                                 const float* __restrict__ g,
                                                 const float* __restrict__ b) {
  const int row = blockIdx.x, t = threadIdx.x;
  const int k = row >> 12;
  float* base = out + (size_t)row * 512;
  float2 x = ((float2*)base)[t];
  float s = x.x + x.y, sq = x.x * x.x + x.y * x.y;
#pragma unroll
  for (int m = 1; m < 64; m <<= 1) {
    s += __shfl_xor(s, m, 64);
    sq += __shfl_xor(sq, m, 64);
  }
  __shared__ float S[4], Q[4];
  const int w = t >> 6, lane = t & 63;
  if (lane == 0) { S[w] = s; Q[w] = sq; }
  __syncthreads();
  s = S[0] + S[1] + S[2] + S[3];
  sq = Q[0] + Q[1] + Q[2] + Q[3];
  float mu = s * (1.f / 512.f);
  float var = sq * (1.f / 512.f) - mu * mu;
  float invs = rsqrtf(var + 1e-12f);
  int c0 = 2 * t, c1 = 2 * t + 1;
  float2 y;
  y.x = (x.x - mu) * invs * g[k * 512 + c0] + b[k * 512 + c0];
  y.y = (x.y - mu) * invs * g[k * 512 + c1] + b[k * 512 + c1];
  ((float2*)base)[t] = y;
}

// -------------------------- launcher ---------------------------------------
extern "C" void kernel_launch(void* const* d_in, const int* in_sizes, int n_in,
                              void* d_out, int out_size, void* d_ws, size_t ws_size,
                              hipStream_t stream) {
  const float* embs = (const float*)d_in[0];
  const float* scw = (const float*)d_in[1];
  const float* lat = (const float*)d_in[2];
  const int* ccp = (const int*)d_in[3];
  const float* Wq = (const float*)d_in[4];
  const float* bq = (const float*)d_in[5];
  const float* Wk = (const float*)d_in[6];
  const float* bk = (const float*)d_in[7];
  const float* Wv = (const float*)d_in[8];
  const float* bv = (const float*)d_in[9];
  const float* Wo = (const float*)d_in[10];
  const float* bo = (const float*)d_in[11];
  const float* lng = (const float*)d_in[12];
  const float* lnb = (const float*)d_in[13];
  float* out = (float*)d_out;

  char* wsp = (char*)d_ws;
  f16* Eh = (f16*)(wsp);                       // 4MB embs f16
  f16* Wqh = (f16*)(wsp + 0x400000);           // 512KB each
  f16* Wkh = (f16*)(wsp + 0x480000);
  f16* Wvh = (f16*)(wsp + 0x500000);
  f16* Woh = (f16*)(wsp + 0x580000);
  f16* qh = (f16*)(wsp + 0x600000);            // 4MB
  f16* kh = (f16*)(wsp + 0xA00000);            // 4MB
  f16* VT = (f16*)(wsp + 0xE00000);            // 4MB, [512][4096] pre-swizzled
  f16* Ab = (f16*)(wsp + 0x1200000);           // 1.5MB [6][4096][32]
  unsigned* gmax = (unsigned*)(wsp + 0x1380000);
  f16* scores_h = (f16*)(wsp + 0x1400000);     // 32MB [4096][4096] f16
  f16* ctxh = (f16*)(wsp + 0x1400000);         // 24MB overlay (scores dead after rowmax_exp)
  f16* Eexp = (f16*)(wsp + 0x3400000);         // 32MB [4096][4096]
  // peak ws use: 0x5400000 = 84MB

  dim3 b256(256);

  cvt_f16_kernel<<<2048, b256, 0, stream>>>(embs, Eh, 524288);
  cvt_f16_kernel<<<256, b256, 0, stream>>>(Wq, Wqh, 65536);
  cvt_f16_kernel<<<256, b256, 0, stream>>>(Wk, Wkh, 65536);
  cvt_f16_kernel<<<256, b256, 0, stream>>>(Wv, Wvh, 65536);
  cvt_f16_kernel<<<256, b256, 0, stream>>>(Wo, Woh, 65536);
  build_A_kernel<<<3072, b256, 0, stream>>>(scw, lat, ccp, Ab, 786432);
  hipMemsetAsync(gmax, 0, 64, stream);

  const float qscale = 0.044194173824159216f;  // 1/sqrt(512)
  gemm_bt<0><<<dim3(32, 4), b256, 0, stream>>>(Eh, Wqh, bq, nullptr, nullptr, qh,
                                               4096, 512, 512, 512, qscale);
  gemm_bt<0><<<dim3(32, 4), b256, 0, stream>>>(Eh, Wkh, bk, nullptr, nullptr, kh,
                                               4096, 512, 512, 512, 1.f);
  gemm_bt<1><<<dim3(32, 4), b256, 0, stream>>>(Eh, Wvh, bv, nullptr, nullptr, VT,
                                               4096, 512, 512, 512, 1.f);
  gemm_bt<4><<<dim3(32, 32), b256, 0, stream>>>(qh, kh, nullptr, nullptr, nullptr, scores_h,
                                                4096, 4096, 512, 4096, 1.f);
  diag_max_kernel<<<96, b256, 0, stream>>>(Ab, gmax);
  rowmax_exp_kernel<<<4096, b256, 0, stream>>>(scores_h, Eexp);
  attn_pv_kernel<<<dim3(64, 6), 512, 0, stream>>>(Eexp, VT, Ab, gmax, ctxh);
  gemm_bt<3><<<dim3(192, 4), b256, 0, stream>>>(ctxh, Woh, bo, embs, out, nullptr,
                                                24576, 512, 512, 512, 1.f);
  ln_kernel<<<24576, b256, 0, stream>>>(out, lng, lnb);
}

// Round 4
// 413.758 us; speedup vs baseline: 1.0166x; 1.0166x over previous
//
#include <hip/hip_runtime.h>

// ---------------------------------------------------------------------------
// IntraStockCorrelation: N=4096, H=512, C=16, K=6
// softmax(scores + log(gram/max + 1e-10)) == es*g / sum(es*g),
//   es = exp(scores - rowmax(scores)) (shared over k), g = gram*inv + 1e-10
// Gram is PSD -> max entry on diagonal -> diag-only max (fused into build_A).
// attn_pv2: 768 balanced blocks, dbuf staging, raw barriers, vmcnt(0) at
// phase end only (1-deep pipeline).  wo_ln: GEMM+bias+residual+LN fused.
// ---------------------------------------------------------------------------

typedef _Float16 f16;
typedef _Float16 v8h __attribute__((ext_vector_type(8)));
typedef _Float16 v4h __attribute__((ext_vector_type(4)));
typedef float f32x4 __attribute__((ext_vector_type(4)));

#define MFMA_F16(a, b, c) __builtin_amdgcn_mfma_f32_16x16x32_f16(a, b, c, 0, 0, 0)

#define GLOAD16(gp, lp)                                                        \
  __builtin_amdgcn_global_load_lds(                                            \
      (const __attribute__((address_space(1))) void*)(gp),                     \
      (__attribute__((address_space(3))) void*)(lp), 16, 0, 0)

#define FENCE asm volatile("" ::: "memory")
#define WAIT_LGKM0                                                             \
  {                                                                            \
    asm volatile("s_waitcnt lgkmcnt(0)" ::: "memory");                         \
    __builtin_amdgcn_sched_barrier(0);                                         \
  }
#define WAIT_VM0                                                               \
  {                                                                            \
    asm volatile("s_waitcnt vmcnt(0)" ::: "memory");                           \
    __builtin_amdgcn_sched_barrier(0);                                         \
  }
#define BARRIER                                                                \
  {                                                                            \
    FENCE;                                                                     \
    __builtin_amdgcn_s_barrier();                                              \
    FENCE;                                                                     \
    __builtin_amdgcn_sched_barrier(0);                                         \
  }

// -------------------------- fused conversions ------------------------------
// [0,524288): embs f32->f16 ; [524288,786432): Wq|Wk|Wv|Wo -> Wcat f16 ;
// [786432,786816): bq|bk|bv -> bcat f32
__global__ void cvt_all_kernel(const float* __restrict__ embs,
                               const float* __restrict__ Wq, const float* __restrict__ Wk,
                               const float* __restrict__ Wv, const float* __restrict__ Wo,
                               const float* __restrict__ bq, const float* __restrict__ bk,
                               const float* __restrict__ bv,
                               f16* __restrict__ Eh, f16* __restrict__ Wcat,
                               float* __restrict__ bcat) {
  int i = blockIdx.x * 256 + threadIdx.x;
  if (i < 524288) {
    float4 v = ((const float4*)embs)[i];
    v4h o = {(f16)v.x, (f16)v.y, (f16)v.z, (f16)v.w};
    ((v4h*)Eh)[i] = o;
  } else if (i < 786432) {
    int widx = i - 524288;
    int r = widx >> 16;
    const float* src = (r == 0) ? Wq : (r == 1) ? Wk : (r == 2) ? Wv : Wo;
    float4 v = ((const float4*)src)[widx & 65535];
    v4h o = {(f16)v.x, (f16)v.y, (f16)v.z, (f16)v.w};
    ((v4h*)Wcat)[widx] = o;
  } else if (i < 786816) {
    int bidx = i - 786432;
    int r = bidx >> 7;
    const float* src = (r == 0) ? bq : (r == 1) ? bk : bv;
    ((float4*)bcat)[bidx] = ((const float4*)src)[bidx & 127];
  }
}

// ---------------- build A (f16, zero-padded c32) + fused diag max ----------
__global__ void build_A_kernel(const float* __restrict__ wgt, const float* __restrict__ lat,
                               const int* __restrict__ ccp, f16* __restrict__ Ab,
                               unsigned* __restrict__ gmax) {
  int idx = blockIdx.x * 256 + threadIdx.x;
  int cc = ccp[0];
  int k = idx >> 17;
  int rem = idx & 131071;
  int n = rem >> 5;
  int c = rem & 31;
  float v = 0.f;
  if (c < cc) v = wgt[n * 16 + c] * lat[(n * 16 + c) * 6 + k];
  f16 h = (f16)v;
  Ab[idx] = h;
  // gram diag = ||A_k[n]||^2 ; row occupies one 32-lane half of a wave
  float fv = (float)h;
  float s = fv * fv;
#pragma unroll
  for (int m = 1; m <= 16; m <<= 1) s += __shfl_xor(s, m, 64);
  s = fmaxf(s, __shfl_xor(s, 32, 64));
  __shared__ float red[4];
  int t = threadIdx.x, w = t >> 6;
  if ((t & 63) == 0) red[w] = s;
  __syncthreads();
  if (t == 0) {
    float m4 = fmaxf(fmaxf(red[0], red[1]), fmaxf(red[2], red[3]));
    atomicMax(&gmax[k], __float_as_uint(m4));  // s >= 0: uint order == float order
  }
}

// -------------------------- generic f16 MFMA GEMM (A @ B^T) ----------------
// MODE 4: scores: outh[row*ldo+col] = acc (f16)
// MODE 5: fused qkv: col<512 -> q (scaled), <1024 -> k, else V^T pre-swizzled
template <int MODE>
__global__ __launch_bounds__(256, 2) void gemm_bt(
    const f16* __restrict__ A, const f16* __restrict__ B,
    const float* __restrict__ bias, f16* __restrict__ outh, f16* __restrict__ aux,
    int Kd, int ldo, float alpha) {
  __shared__ f16 As[128 * 32];
  __shared__ f16 Bs[128 * 32];
  const int t = threadIdx.x;
  const int w = t >> 6, lane = t & 63, r15 = lane & 15, r4 = lane >> 4;
  const int wr = w >> 1, wc = w & 1;
  const int row0 = blockIdx.x * 128, col0 = blockIdx.y * 128;

  f32x4 acc[4][4] = {};
  const f16* Ap = A + (size_t)(row0 + (t >> 2)) * Kd + (t & 3) * 8;
  const f16* Bp = B + (size_t)(col0 + (t >> 2)) * Kd + (t & 3) * 8;

  for (int k0 = 0; k0 < Kd; k0 += 32) {
    __syncthreads();
    GLOAD16(Ap + k0, &As[t * 8]);
    GLOAD16(Ap + k0 + (size_t)64 * Kd, &As[2048 + t * 8]);
    GLOAD16(Bp + k0, &Bs[t * 8]);
    GLOAD16(Bp + k0 + (size_t)64 * Kd, &Bs[2048 + t * 8]);
    __syncthreads();
    v8h a[4], b[4];
#pragma unroll
    for (int f = 0; f < 4; ++f) a[f] = *(const v8h*)&As[(wr * 64 + f * 16 + r15) * 32 + r4 * 8];
#pragma unroll
    for (int f = 0; f < 4; ++f) b[f] = *(const v8h*)&Bs[(wc * 64 + f * 16 + r15) * 32 + r4 * 8];
#pragma unroll
    for (int i = 0; i < 4; ++i)
#pragma unroll
      for (int j = 0; j < 4; ++j) acc[i][j] = MFMA_F16(a[i], b[j], acc[i][j]);
  }

#pragma unroll
  for (int i = 0; i < 4; ++i) {
#pragma unroll
    for (int j = 0; j < 4; ++j) {
#pragma unroll
      for (int r = 0; r < 4; ++r) {
        int row = row0 + wr * 64 + i * 16 + r4 * 4 + r;
        int col = col0 + wc * 64 + j * 16 + r15;
        float v = acc[i][j][r];
        if constexpr (MODE == 4) {
          outh[(size_t)row * ldo + col] = (f16)v;
        } else {
          float vv = v + bias[col];
          int reg = col >> 9;
          if (reg < 2) {
            float sc = (reg == 0) ? alpha : 1.f;
            outh[(size_t)reg * 2097152 + (size_t)row * 512 + (col & 511)] = (f16)(vv * sc);
          } else {
            int cv = col & 511;
            aux[(size_t)cv * 4096 + (size_t)(row & ~31) + (size_t)((row & 31) ^ ((cv & 3) << 3))] =
                (f16)vv;
          }
        }
      }
    }
  }
}

// -------------------------- rowmax + exp (f16 scores) ----------------------
__global__ __launch_bounds__(256) void rowmax_exp_kernel(const f16* __restrict__ scores,
                                                         f16* __restrict__ Eexp) {
  const int row = blockIdx.x, t = threadIdx.x;
  const v8h* src = (const v8h*)(scores + (size_t)row * 4096);
  v8h v0 = src[t], v1 = src[t + 256];
  float m = -3.4e38f;
#pragma unroll
  for (int j = 0; j < 8; ++j) m = fmaxf(m, fmaxf((float)v0[j], (float)v1[j]));
#pragma unroll
  for (int msk = 1; msk < 64; msk <<= 1) m = fmaxf(m, __shfl_xor(m, msk, 64));
  __shared__ float red[4];
  const int w = t >> 6, lane = t & 63;
  if (lane == 0) red[w] = m;
  __syncthreads();
  m = fmaxf(fmaxf(red[0], red[1]), fmaxf(red[2], red[3]));
  v8h o0, o1;
#pragma unroll
  for (int j = 0; j < 8; ++j) {
    o0[j] = (f16)__expf((float)v0[j] - m);
    o1[j] = (f16)__expf((float)v1[j] - m);
  }
  v8h* dst = (v8h*)(Eexp + (size_t)row * 4096);
  dst[t] = o0;
  dst[t + 256] = o1;
}

// -------------------------- fused mask+softmax+PV (v2) ---------------------
// 768 blocks (= 3/CU exact): 64 rows x 256 Hcols x (k,hh).  4 waves.
// Double-buffered Vt/E/gb; raw barriers; vmcnt(0) drain at phase end only.
__global__ __launch_bounds__(256, 3) void attn_pv2_kernel(
    const f16* __restrict__ Eexp, const f16* __restrict__ VT,
    const f16* __restrict__ Ab, const unsigned* __restrict__ gmax,
    f16* __restrict__ ctx) {
  __shared__ f16 Vt_s[2][256 * 32];  // 16KB x2 (pre-swizzled via VT)
  __shared__ f16 E_s[2][64 * 32];    // 4KB x2 (r4-XOR swizzled via source)
  __shared__ f16 P_s[64 * 32];       // 4KB (r4-XOR swizzled)
  __shared__ float denom_s[64];

  const int t = threadIdx.x;
  const int w = t >> 6, lane = t & 63, r15 = lane & 15, r4 = lane >> 4;

  // XCD remap: each XCD owns 8 row-strips x 12 (hh,k) variants
  int d = blockIdx.x;
  int xcd = d & 7, jj6 = d >> 3;
  int strip = xcd * 8 + jj6 / 12;
  int sub = jj6 % 12;
  int hh = sub / 6, kk = sub - (sub / 6) * 6;
  const int row0 = strip * 64;
  const int h0 = hh * 256;

  const float inv = 1.f / (__uint_as_float(gmax[kk]) + 1e-8f);
  const f16* Abk = Ab + (size_t)kk * 4096 * 32;

  // gram A-frag (rows n), loop-invariant
  v8h ga = *(const v8h*)(Abk + (size_t)(row0 + w * 16 + r15) * 32 + r4 * 8);

  f32x4 acc[4][4] = {};
  float dpart[4] = {0.f, 0.f, 0.f, 0.f};
  f32x4 zero4 = {};

#define ATTN_STAGE(P, M0S)                                                     \
  {                                                                            \
    _Pragma("unroll") for (int i2 = 0; i2 < 4; ++i2)                           \
        GLOAD16(VT + (size_t)(h0 + i2 * 64 + (t >> 2)) * 4096 + (M0S) + (t & 3) * 8, \
                &Vt_s[P][i2 * 2048 + t * 8]);                                  \
    {                                                                          \
      int nn = t >> 2;                                                         \
      int cs = (t & 3) ^ ((nn >> 2) & 3);                                      \
      GLOAD16(Eexp + (size_t)(row0 + nn) * 4096 + (M0S) + cs * 8, &E_s[P][t * 8]); \
    }                                                                          \
  }

#define ATTN_COMPUTE(P, GB)                                                    \
  {                                                                            \
    f32x4 g0 = MFMA_F16(ga, GB[0], zero4);                                     \
    f32x4 g1 = MFMA_F16(ga, GB[1], zero4);                                     \
    _Pragma("unroll") for (int r = 0; r < 4; ++r) {                            \
      int nl = w * 16 + r4 * 4 + r;                                            \
      int xo = r4 << 3;                                                        \
      float e0 = (float)E_s[P][nl * 32 + (r15 ^ xo)];                          \
      float e1 = (float)E_s[P][nl * 32 + ((16 + r15) ^ xo)];                   \
      float p0 = e0 * (g0[r] * inv + 1e-10f);                                  \
      float p1 = e1 * (g1[r] * inv + 1e-10f);                                  \
      dpart[r] += p0 + p1;                                                     \
      P_s[nl * 32 + (r15 ^ xo)] = (f16)p0;                                     \
      P_s[nl * 32 + ((16 + r15) ^ xo)] = (f16)p1;                              \
    }                                                                          \
    WAIT_LGKM0;                                                                \
    BARRIER;                                                                   \
    v8h pa[4], vb[4];                                                          \
    _Pragma("unroll") for (int f = 0; f < 4; ++f) {                            \
      int n2 = f * 16 + r15;                                                   \
      pa[f] = *(const v8h*)&P_s[n2 * 32 + ((r4 * 8) ^ (((n2 >> 2) & 3) << 3))];\
      int hl = w * 64 + f * 16 + r15;                                          \
      vb[f] = *(const v8h*)&Vt_s[P][hl * 32 + ((r4 * 8) ^ ((hl & 3) << 3))];   \
    }                                                                          \
    __builtin_amdgcn_s_setprio(1);                                             \
    _Pragma("unroll") for (int i = 0; i < 4; ++i)                              \
        _Pragma("unroll") for (int j2 = 0; j2 < 4; ++j2)                       \
            acc[i][j2] = MFMA_F16(pa[i], vb[j2], acc[i][j2]);                  \
    __builtin_amdgcn_s_setprio(0);                                             \
    WAIT_LGKM0;                                                                \
    WAIT_VM0;                                                                  \
    BARRIER;                                                                   \
  }

  // prologue: stage phase 0, drain, barrier
  ATTN_STAGE(0, 0);
  v8h gb0[2], gb1[2];
  gb0[0] = *(const v8h*)(Abk + (size_t)(0 + r15) * 32 + r4 * 8);
  gb0[1] = *(const v8h*)(Abk + (size_t)(16 + r15) * 32 + r4 * 8);
  WAIT_VM0;
  BARRIER;

  for (int mc = 0; mc < 128; mc += 2) {
    int mn = (mc + 1) * 32;
    ATTN_STAGE(1, mn);
    gb1[0] = *(const v8h*)(Abk + (size_t)(mn + r15) * 32 + r4 * 8);
    gb1[1] = *(const v8h*)(Abk + (size_t)(mn + 16 + r15) * 32 + r4 * 8);
    ATTN_COMPUTE(0, gb0);
    int mn2 = (mc + 2 < 128) ? (mc + 2) * 32 : 0;
    ATTN_STAGE(0, mn2);
    gb0[0] = *(const v8h*)(Abk + (size_t)(mn2 + r15) * 32 + r4 * 8);
    gb0[1] = *(const v8h*)(Abk + (size_t)(mn2 + 16 + r15) * 32 + r4 * 8);
    ATTN_COMPUTE(1, gb1);
  }

  // denominators: each wave owns rows w*16..w*16+15, summed over all m
#pragma unroll
  for (int r = 0; r < 4; ++r) {
#pragma unroll
    for (int msk = 1; msk < 16; msk <<= 1) dpart[r] += __shfl_xor(dpart[r], msk, 64);
  }
  if (r15 == 0) {
#pragma unroll
    for (int r = 0; r < 4; ++r) denom_s[w * 16 + r4 * 4 + r] = dpart[r];
  }
  __syncthreads();
#pragma unroll
  for (int i = 0; i < 4; ++i) {
#pragma unroll
    for (int r = 0; r < 4; ++r) {
      int n = i * 16 + r4 * 4 + r;
      float invd = 1.f / denom_s[n];
#pragma unroll
      for (int j = 0; j < 4; ++j) {
        ctx[((size_t)(kk * 4096 + row0 + n)) * 512 + h0 + w * 64 + j * 16 + r15] =
            (f16)(acc[i][j][r] * invd);
      }
    }
  }
#undef ATTN_STAGE
#undef ATTN_COMPUTE
}

// ---------------- fused ctx@Wo^T + bias + residual + LayerNorm -------------
// 512 blocks x 512 thr (= 2/CU exact): 48 rows x full 512 cols each.
__global__ __launch_bounds__(512, 4) void wo_ln_kernel(
    const f16* __restrict__ ctxh, const f16* __restrict__ Woh,
    const float* __restrict__ bo, const float* __restrict__ embs,
    const float* __restrict__ lng, const float* __restrict__ lnb,
    float* __restrict__ out) {
  __shared__ f16 As_[2][48 * 32];    // 3KB x2
  __shared__ f16 Bs_[2][512 * 32];   // 32KB x2
  __shared__ float redS[8][48];
  __shared__ float redQ[8][48];
  __shared__ float muS[48], ivS[48];

  const int t = threadIdx.x;
  const int w = t >> 6, lane = t & 63, r15 = lane & 15, r4 = lane >> 4;
  const int row0 = blockIdx.x * 48;
  const int wm3 = w % 3;
  const int caRow = wm3 * 64 + lane;  // As chunk (duplicated across wave triples)

  f32x4 acc[3][4] = {};

#define WO_STAGE(P, KQ)                                                        \
  {                                                                            \
    GLOAD16(ctxh + (size_t)(row0 + (caRow >> 2)) * 512 + (KQ) + (caRow & 3) * 8, \
            &As_[P][caRow * 8]);                                               \
    _Pragma("unroll") for (int q2 = 0; q2 < 4; ++q2)                           \
        GLOAD16(Woh + (size_t)((q2 * 512 + t) >> 2) * 512 + (KQ) + (t & 3) * 8,\
                &Bs_[P][(q2 * 512 + t) * 8]);                                  \
  }

#define WO_COMPUTE(P)                                                          \
  {                                                                            \
    v8h a[3], b[4];                                                            \
    _Pragma("unroll") for (int i = 0; i < 3; ++i)                              \
        a[i] = *(const v8h*)&As_[P][(i * 16 + r15) * 32 + r4 * 8];             \
    _Pragma("unroll") for (int j = 0; j < 4; ++j)                              \
        b[j] = *(const v8h*)&Bs_[P][(w * 64 + j * 16 + r15) * 32 + r4 * 8];    \
    __builtin_amdgcn_s_setprio(1);                                             \
    _Pragma("unroll") for (int i = 0; i < 3; ++i)                              \
        _Pragma("unroll") for (int j = 0; j < 4; ++j)                          \
            acc[i][j] = MFMA_F16(a[i], b[j], acc[i][j]);                       \
    __builtin_amdgcn_s_setprio(0);                                             \
    WAIT_LGKM0;                                                                \
    WAIT_VM0;                                                                  \
    BARRIER;                                                                   \
  }

  WO_STAGE(0, 0);
  WAIT_VM0;
  BARRIER;
  for (int kq = 0; kq < 16; kq += 2) {
    WO_STAGE(1, (kq + 1) * 32);
    WO_COMPUTE(0);
    int k2 = (kq + 2 < 16) ? (kq + 2) * 32 : 0;
    WO_STAGE(0, k2);
    WO_COMPUTE(1);
  }
#undef WO_STAGE
#undef WO_COMPUTE

  // bias + residual, then LN stats
  float sS[3][4], sQ[3][4];
#pragma unroll
  for (int i = 0; i < 3; ++i) {
#pragma unroll
    for (int r = 0; r < 4; ++r) {
      int R = row0 + i * 16 + r4 * 4 + r;
      int er = R & 4095;
      float s = 0.f, q = 0.f;
#pragma unroll
      for (int j = 0; j < 4; ++j) {
        int col = w * 64 + j * 16 + r15;
        float v = acc[i][j][r] + bo[col] + embs[(size_t)er * 512 + col];
        acc[i][j][r] = v;
        s += v;
        q += v * v;
      }
      sS[i][r] = s;
      sQ[i][r] = q;
    }
  }
#pragma unroll
  for (int i = 0; i < 3; ++i)
#pragma unroll
    for (int r = 0; r < 4; ++r)
#pragma unroll
      for (int msk = 1; msk < 16; msk <<= 1) {
        sS[i][r] += __shfl_xor(sS[i][r], msk, 64);
        sQ[i][r] += __shfl_xor(sQ[i][r], msk, 64);
      }
  if (r15 == 0) {
#pragma unroll
    for (int i = 0; i < 3; ++i)
#pragma unroll
      for (int r = 0; r < 4; ++r) {
        redS[w][i * 16 + r4 * 4 + r] = sS[i][r];
        redQ[w][i * 16 + r4 * 4 + r] = sQ[i][r];
      }
  }
  __syncthreads();
  if (t < 48) {
    float s = 0.f, q = 0.f;
#pragma unroll
    for (int wv = 0; wv < 8; ++wv) {
      s += redS[wv][t];
      q += redQ[wv][t];
    }
    float mu = s * (1.f / 512.f);
    float var = q * (1.f / 512.f) - mu * mu;
    muS[t] = mu;
    ivS[t] = rsqrtf(var + 1e-12f);
  }
  __syncthreads();
#pragma unroll
  for (int i = 0; i < 3; ++i) {
#pragma unroll
    for (int r = 0; r < 4; ++r) {
      int n = i * 16 + r4 * 4 + r;
      int R = row0 + n;
      int k = R >> 12;
      float mu = muS[n], iv = ivS[n];
#pragma unroll
      for (int j = 0; j < 4; ++j) {
        int col = w * 64 + j * 16 + r15;
        out[(size_t)R * 512 + col] =
            (acc[i][j][r] - mu) * iv * lng[k * 512 + col] + lnb[k * 512 + col];
      }
    }
  }
}

// -------------------------- launcher ---------------------------------------
extern "C" void kernel_launch(void* const* d_in, const int* in_sizes, int n_in,
                              void* d_out, int out_size, void* d_ws, size_t ws_size,
                              hipStream_t stream) {
  const float* embs = (const float*)d_in[0];
  const float* scw = (const float*)d_in[1];
  const float* lat = (const float*)d_in[2];
  const int* ccp = (const int*)d_in[3];
  const float* Wq = (const float*)d_in[4];
  const float* bq = (const float*)d_in[5];
  const float* Wk = (const float*)d_in[6];
  const float* bk = (const float*)d_in[7];
  const float* Wv = (const float*)d_in[8];
  const float* bv = (const float*)d_in[9];
  const float* Wo = (const float*)d_in[10];
  const float* bo = (const float*)d_in[11];
  const float* lng = (const float*)d_in[12];
  const float* lnb = (const float*)d_in[13];
  float* out = (float*)d_out;

  char* wsp = (char*)d_ws;
  f16* Eh = (f16*)(wsp);                      // 4MB
  f16* Wcat = (f16*)(wsp + 0x400000);         // 2MB: Wq|Wk|Wv|Wo f16
  f16* Woh = (f16*)(wsp + 0x580000);          // last 512KB of Wcat
  f16* qh = (f16*)(wsp + 0x600000);           // 4MB q | 4MB k (contiguous)
  f16* VT = (f16*)(wsp + 0xE00000);           // 4MB [512][4096] pre-swizzled
  f16* Ab = (f16*)(wsp + 0x1200000);          // 1.5MB [6][4096][32]
  unsigned* gmax = (unsigned*)(wsp + 0x1380000);
  float* bcat = (float*)(wsp + 0x1381000);    // 6KB
  f16* scores_h = (f16*)(wsp + 0x1400000);    // 32MB
  f16* ctxh = (f16*)(wsp + 0x1400000);        // 24MB overlay (scores dead after rowmax)
  f16* Eexp = (f16*)(wsp + 0x3400000);        // 32MB

  dim3 b256(256);
  const float qscale = 0.044194173824159216f;  // 1/sqrt(512)

  hipMemsetAsync(gmax, 0, 64, stream);
  cvt_all_kernel<<<3074, b256, 0, stream>>>(embs, Wq, Wk, Wv, Wo, bq, bk, bv,
                                            Eh, Wcat, bcat);
  build_A_kernel<<<3072, b256, 0, stream>>>(scw, lat, ccp, Ab, gmax);
  gemm_bt<5><<<dim3(32, 12), b256, 0, stream>>>(Eh, Wcat, bcat, qh, VT,
                                                512, 512, qscale);
  gemm_bt<4><<<dim3(32, 32), b256, 0, stream>>>(qh, qh + 2097152, nullptr, scores_h,
                                                nullptr, 512, 4096, 1.f);
  rowmax_exp_kernel<<<4096, b256, 0, stream>>>(scores_h, Eexp);
  attn_pv2_kernel<<<768, b256, 0, stream>>>(Eexp, VT, Ab, gmax, ctxh);
  wo_ln_kernel<<<512, 512, 0, stream>>>(ctxh, Woh, bo, embs, lng, lnb, out);
}